// Round 1
// baseline (5917.245 us; speedup 1.0000x reference)
//
#include <hip/hip_runtime.h>

#define HW 147456          // 384*384
#define NWIN_B 2304        // 48*48 windows per batch image

// ---------------------------------------------------------------------------
// Kernel A: shifted-window MHA + out-proj + residual.  One block per window.
// LDS: sT[c][tok] (24KB) | sQKV[dim][tok] (72KB) | sO[tok][c] s97 (24.8KB)
//      sW staging buffer (36KB)  -> total 160,000 B (<= 163,840 on gfx950)
// ---------------------------------------------------------------------------
__global__ __launch_bounds__(256) void wa_attn(
    const float* __restrict__ x, const float* __restrict__ ipw,
    const float* __restrict__ ipb, const float* __restrict__ opw,
    const float* __restrict__ opb, const float* __restrict__ bt,
    float* __restrict__ y)
{
  __shared__ __align__(16) float sT[6144];     // [96][64]
  __shared__ __align__(16) float sQKV[18432];  // [288][64]
  __shared__ __align__(16) float sO[6208];     // [64][97]
  __shared__ __align__(16) float sW[9216];     // [96][96] staged weights

  const int tid = threadIdx.x;
  const int wid = blockIdx.x;
  const int b   = wid / NWIN_B;
  const int rem = wid - b * NWIN_B;
  const int wy  = rem / 48;
  const int wx  = rem - wy * 48;
  const int tok = tid & 63;
  const int wv  = __builtin_amdgcn_readfirstlane(tid >> 6);  // wave id 0..3

  // ---- Phase 1: gather shifted window tokens into sT[c][tok] --------------
  #pragma unroll
  for (int i = 0; i < 24; ++i) {
    int idx = i * 256 + tid;
    int c = idx >> 6, t = idx & 63;
    int hh = (wy << 3) + (t >> 3) + 4; if (hh >= 384) hh -= 384;
    int ww = (wx << 3) + (t & 7) + 4;  if (ww >= 384) ww -= 384;
    sT[idx] = x[(b * 96 + c) * HW + hh * 384 + ww];
  }

  // ---- Phase 2: qkv = t @ ipw^T + ipb, stored [dim][tok] ------------------
  for (int chunk = 0; chunk < 3; ++chunk) {
    __syncthreads();                       // sT ready / prev chunk consumed
    #pragma unroll
    for (int i = 0; i < 36; ++i)
      sW[i * 256 + tid] = ipw[chunk * 9216 + i * 256 + tid];
    __syncthreads();
    #pragma unroll 1
    for (int g = 0; g < 6; ++g) {
      int bl  = g * 16 + wv * 4;           // local dim base (0..95)
      int dim = chunk * 96 + bl;
      float a0 = ipb[dim], a1 = ipb[dim + 1], a2 = ipb[dim + 2], a3 = ipb[dim + 3];
      #pragma unroll
      for (int c4 = 0; c4 < 24; ++c4) {
        float t0 = sT[(c4 * 4 + 0) * 64 + tok];
        float t1 = sT[(c4 * 4 + 1) * 64 + tok];
        float t2 = sT[(c4 * 4 + 2) * 64 + tok];
        float t3 = sT[(c4 * 4 + 3) * 64 + tok];
        float4 w0 = *(const float4*)&sW[(bl + 0) * 96 + c4 * 4];
        float4 w1 = *(const float4*)&sW[(bl + 1) * 96 + c4 * 4];
        float4 w2 = *(const float4*)&sW[(bl + 2) * 96 + c4 * 4];
        float4 w3 = *(const float4*)&sW[(bl + 3) * 96 + c4 * 4];
        a0 += w0.x * t0 + w0.y * t1 + w0.z * t2 + w0.w * t3;
        a1 += w1.x * t0 + w1.y * t1 + w1.z * t2 + w1.w * t3;
        a2 += w2.x * t0 + w2.y * t1 + w2.z * t2 + w2.w * t3;
        a3 += w3.x * t0 + w3.y * t1 + w3.z * t2 + w3.w * t3;
      }
      sQKV[(dim + 0) * 64 + tok] = a0;
      sQKV[(dim + 1) * 64 + tok] = a1;
      sQKV[(dim + 2) * 64 + tok] = a2;
      sQKV[(dim + 3) * 64 + tok] = a3;
    }
  }
  __syncthreads();

  // ---- Phase 3: scores + softmax + PV (registers + shfl) ------------------
  const int it = tid >> 4, jt = tid & 15;
  const int i0 = it << 2, j0 = jt << 2;

  float msk[16];
  #pragma unroll
  for (int a = 0; a < 4; ++a) {
    int ri = (i0 + a) >> 3, ci = (i0 + a) & 7;
    #pragma unroll
    for (int bb = 0; bb < 4; ++bb) {
      int rj = (j0 + bb) >> 3, cj = (j0 + bb) & 7;
      msk[a * 4 + bb] = bt[(ri - rj + 7) * 15 + (ci - cj + 7)];
    }
  }

  #pragma unroll 1
  for (int h = 0; h < 2; ++h) {
    const float* qp = sQKV + (h * 48) * 64;
    const float* kp = sQKV + (96 + h * 48) * 64;
    const float* vp = sQKV + (192 + h * 48) * 64;
    float acc[16];
    #pragma unroll
    for (int i = 0; i < 16; ++i) acc[i] = 0.f;
    #pragma unroll 4
    for (int d = 0; d < 48; ++d) {
      float4 q4 = *(const float4*)(qp + d * 64 + i0);
      float4 k4 = *(const float4*)(kp + d * 64 + j0);
      acc[0]  += q4.x * k4.x; acc[1]  += q4.x * k4.y; acc[2]  += q4.x * k4.z; acc[3]  += q4.x * k4.w;
      acc[4]  += q4.y * k4.x; acc[5]  += q4.y * k4.y; acc[6]  += q4.y * k4.z; acc[7]  += q4.y * k4.w;
      acc[8]  += q4.z * k4.x; acc[9]  += q4.z * k4.y; acc[10] += q4.z * k4.z; acc[11] += q4.z * k4.w;
      acc[12] += q4.w * k4.x; acc[13] += q4.w * k4.y; acc[14] += q4.w * k4.z; acc[15] += q4.w * k4.w;
    }
    #pragma unroll
    for (int i = 0; i < 16; ++i)
      acc[i] = acc[i] * 0.14433756729740643f + msk[i];

    #pragma unroll
    for (int a = 0; a < 4; ++a) {
      float m0 = fmaxf(fmaxf(acc[a*4], acc[a*4+1]), fmaxf(acc[a*4+2], acc[a*4+3]));
      m0 = fmaxf(m0, __shfl_xor(m0, 1));
      m0 = fmaxf(m0, __shfl_xor(m0, 2));
      m0 = fmaxf(m0, __shfl_xor(m0, 4));
      m0 = fmaxf(m0, __shfl_xor(m0, 8));
      float e0 = __expf(acc[a*4+0] - m0);
      float e1 = __expf(acc[a*4+1] - m0);
      float e2 = __expf(acc[a*4+2] - m0);
      float e3 = __expf(acc[a*4+3] - m0);
      float s0 = e0 + e1 + e2 + e3;
      s0 += __shfl_xor(s0, 1);
      s0 += __shfl_xor(s0, 2);
      s0 += __shfl_xor(s0, 4);
      s0 += __shfl_xor(s0, 8);
      float r = 1.0f / s0;
      acc[a*4+0] = e0 * r; acc[a*4+1] = e1 * r; acc[a*4+2] = e2 * r; acc[a*4+3] = e3 * r;
    }

    #pragma unroll 2
    for (int d = 0; d < 48; ++d) {
      float4 v4 = *(const float4*)(vp + d * 64 + j0);
      float o0 = acc[0]  * v4.x + acc[1]  * v4.y + acc[2]  * v4.z + acc[3]  * v4.w;
      float o1 = acc[4]  * v4.x + acc[5]  * v4.y + acc[6]  * v4.z + acc[7]  * v4.w;
      float o2 = acc[8]  * v4.x + acc[9]  * v4.y + acc[10] * v4.z + acc[11] * v4.w;
      float o3 = acc[12] * v4.x + acc[13] * v4.y + acc[14] * v4.z + acc[15] * v4.w;
      o0 += __shfl_xor(o0, 1); o0 += __shfl_xor(o0, 2); o0 += __shfl_xor(o0, 4); o0 += __shfl_xor(o0, 8);
      o1 += __shfl_xor(o1, 1); o1 += __shfl_xor(o1, 2); o1 += __shfl_xor(o1, 4); o1 += __shfl_xor(o1, 8);
      o2 += __shfl_xor(o2, 1); o2 += __shfl_xor(o2, 2); o2 += __shfl_xor(o2, 4); o2 += __shfl_xor(o2, 8);
      o3 += __shfl_xor(o3, 1); o3 += __shfl_xor(o3, 2); o3 += __shfl_xor(o3, 4); o3 += __shfl_xor(o3, 8);
      if (jt == 0) {
        int cc = h * 48 + d;
        sO[(i0 + 0) * 97 + cc] = o0;
        sO[(i0 + 1) * 97 + cc] = o1;
        sO[(i0 + 2) * 97 + cc] = o2;
        sO[(i0 + 3) * 97 + cc] = o3;
      }
    }
  }
  __syncthreads();

  // ---- Phase 4: out-proj + residual, write y ------------------------------
  #pragma unroll
  for (int i = 0; i < 36; ++i)
    sW[i * 256 + tid] = opw[i * 256 + tid];
  __syncthreads();

  int hh = (wy << 3) + (tok >> 3) + 4; if (hh >= 384) hh -= 384;
  int ww = (wx << 3) + (tok & 7) + 4;  if (ww >= 384) ww -= 384;
  const int pix = hh * 384 + ww;

  #pragma unroll 1
  for (int g = 0; g < 6; ++g) {
    int bl = g * 16 + wv * 4;
    float a0 = opb[bl], a1 = opb[bl + 1], a2 = opb[bl + 2], a3 = opb[bl + 3];
    #pragma unroll
    for (int c4 = 0; c4 < 24; ++c4) {
      float t0 = sO[tok * 97 + c4 * 4 + 0];
      float t1 = sO[tok * 97 + c4 * 4 + 1];
      float t2 = sO[tok * 97 + c4 * 4 + 2];
      float t3 = sO[tok * 97 + c4 * 4 + 3];
      float4 w0 = *(const float4*)&sW[(bl + 0) * 96 + c4 * 4];
      float4 w1 = *(const float4*)&sW[(bl + 1) * 96 + c4 * 4];
      float4 w2 = *(const float4*)&sW[(bl + 2) * 96 + c4 * 4];
      float4 w3 = *(const float4*)&sW[(bl + 3) * 96 + c4 * 4];
      a0 += w0.x * t0 + w0.y * t1 + w0.z * t2 + w0.w * t3;
      a1 += w1.x * t0 + w1.y * t1 + w1.z * t2 + w1.w * t3;
      a2 += w2.x * t0 + w2.y * t1 + w2.z * t2 + w2.w * t3;
      a3 += w3.x * t0 + w3.y * t1 + w3.z * t2 + w3.w * t3;
    }
    y[(b * 96 + bl + 0) * HW + pix] = sT[(bl + 0) * 64 + tok] + a0;
    y[(b * 96 + bl + 1) * HW + pix] = sT[(bl + 1) * 64 + tok] + a1;
    y[(b * 96 + bl + 2) * HW + pix] = sT[(bl + 2) * 64 + tok] + a2;
    y[(b * 96 + bl + 3) * HW + pix] = sT[(bl + 3) * 64 + tok] + a3;
  }
}

// ---------------------------------------------------------------------------
// Kernel B: 1x1 conv + exact GELU.  One pixel per thread, W1 staged in LDS.
// ---------------------------------------------------------------------------
__global__ __launch_bounds__(256) void wa_conv1(
    const float* __restrict__ y, const float* __restrict__ w1,
    const float* __restrict__ b1, float* __restrict__ hdn)
{
  __shared__ __align__(16) float sW[9216];
  __shared__ float sB[96];
  const int tid = threadIdx.x;
  #pragma unroll
  for (int i = 0; i < 36; ++i) sW[i * 256 + tid] = w1[i * 256 + tid];
  if (tid < 96) sB[tid] = b1[tid];
  __syncthreads();

  const int pix = blockIdx.x * 256 + tid;      // 0 .. 589823
  const int b  = pix / HW;
  const int hw = pix - b * HW;
  const float* yp = y + (b * 96) * HW + hw;
  float* hp = hdn + (b * 96) * HW + hw;

  float yv[96];
  #pragma unroll
  for (int c = 0; c < 96; ++c) yv[c] = yp[c * HW];

  #pragma unroll 1
  for (int o = 0; o < 96; ++o) {
    float a = sB[o];
    const float4* wr = (const float4*)(sW + o * 96);
    #pragma unroll
    for (int c4 = 0; c4 < 24; ++c4) {
      float4 w4 = wr[c4];
      a += w4.x * yv[c4*4+0] + w4.y * yv[c4*4+1] + w4.z * yv[c4*4+2] + w4.w * yv[c4*4+3];
    }
    float g = 0.5f * a * (1.0f + erff(a * 0.70710678118654752f));
    hp[o * HW] = g;
  }
}

// ---------------------------------------------------------------------------
// Kernel C: 3x3 conv (edge-replicate pad) + LeakyReLU(0.1) + residual.
// 16x16 output tile/block; 4 input channels + weight slice staged per barrier.
// ---------------------------------------------------------------------------
__global__ __launch_bounds__(256) void wa_conv2(
    const float* __restrict__ hdn, const float* __restrict__ w2,
    const float* __restrict__ b2, float* __restrict__ out /* also y */)
{
  __shared__ float sH[4 * 324];                 // 4 x 18 x 18
  __shared__ __align__(16) float sW2[4 * 96 * 12];
  const int tid = threadIdx.x;
  const int bid = blockIdx.x;
  const int b  = bid / 576;
  const int r2 = bid - b * 576;
  const int ty = r2 / 24, tx = r2 - ty * 24;
  const int py = tid >> 4, px = tid & 15;
  const int oy = ty * 16 + py, ox = tx * 16 + px;

  float acc[96];
  #pragma unroll
  for (int o = 0; o < 96; ++o) acc[o] = 0.f;

  #pragma unroll 1
  for (int cb = 0; cb < 24; ++cb) {
    __syncthreads();
    for (int i = tid; i < 1296; i += 256) {
      int cl = i / 324; int rr = i - cl * 324;
      int sy = rr / 18, sx = rr - sy * 18;
      int iy = ty * 16 + sy - 1; iy = iy < 0 ? 0 : (iy > 383 ? 383 : iy);
      int ix = tx * 16 + sx - 1; ix = ix < 0 ? 0 : (ix > 383 ? 383 : ix);
      sH[i] = hdn[(b * 96 + cb * 4 + cl) * HW + iy * 384 + ix];
    }
    for (int i = tid; i < 3456; i += 256) {
      int o = i / 36; int rr = i - o * 36;
      int cc = rr / 9, k = rr - cc * 9;
      sW2[(cc * 96 + o) * 12 + k] = w2[(o * 96 + cb * 4 + cc) * 9 + k];
    }
    __syncthreads();
    #pragma unroll 1
    for (int cl = 0; cl < 4; ++cl) {
      const float* hb = sH + cl * 324;
      float p0 = hb[(py + 0) * 18 + px + 0];
      float p1 = hb[(py + 0) * 18 + px + 1];
      float p2 = hb[(py + 0) * 18 + px + 2];
      float p3 = hb[(py + 1) * 18 + px + 0];
      float p4 = hb[(py + 1) * 18 + px + 1];
      float p5 = hb[(py + 1) * 18 + px + 2];
      float p6 = hb[(py + 2) * 18 + px + 0];
      float p7 = hb[(py + 2) * 18 + px + 1];
      float p8 = hb[(py + 2) * 18 + px + 2];
      const float* wb = sW2 + cl * 96 * 12;
      #pragma unroll
      for (int o = 0; o < 96; ++o) {
        float4 wa  = *(const float4*)(wb + o * 12);
        float4 wc  = *(const float4*)(wb + o * 12 + 4);
        float  w8  = wb[o * 12 + 8];
        acc[o] += wa.x * p0 + wa.y * p1 + wa.z * p2
                + wa.w * p3 + wc.x * p4 + wc.y * p5
                + wc.z * p6 + wc.w * p7 + w8 * p8;
      }
    }
  }

  const int base = (b * 96) * HW + oy * 384 + ox;
  #pragma unroll
  for (int o = 0; o < 96; ++o) {
    float v = acc[o] + b2[o];
    v = v >= 0.f ? v : 0.1f * v;
    out[base + o * HW] = out[base + o * HW] + v;
  }
}

// ---------------------------------------------------------------------------
extern "C" void kernel_launch(void* const* d_in, const int* in_sizes, int n_in,
                              void* d_out, int out_size, void* d_ws, size_t ws_size,
                              hipStream_t stream) {
  const float* x   = (const float*)d_in[0];
  const float* ipw = (const float*)d_in[1];
  const float* ipb = (const float*)d_in[2];
  const float* opw = (const float*)d_in[3];
  const float* opb = (const float*)d_in[4];
  const float* c1w = (const float*)d_in[5];
  const float* c1b = (const float*)d_in[6];
  const float* c2w = (const float*)d_in[7];
  const float* c2b = (const float*)d_in[8];
  const float* bt  = (const float*)d_in[9];
  float* y   = (float*)d_out;          // attention residual output lives in d_out
  float* hdn = (float*)d_ws;           // 226,492,416 B scratch for conv-MLP hidden

  wa_attn<<<dim3(4 * NWIN_B), dim3(256), 0, stream>>>(x, ipw, ipb, opw, opb, bt, y);
  wa_conv1<<<dim3(2304), dim3(256), 0, stream>>>(y, c1w, c1b, hdn);
  wa_conv2<<<dim3(2304), dim3(256), 0, stream>>>(hdn, c2w, c2b, y);
}

// Round 2
// 4075.706 us; speedup vs baseline: 1.4518x; 1.4518x over previous
//
#include <hip/hip_runtime.h>

#define HW 147456          // 384*384
#define NWIN_B 2304        // 48*48 windows per batch image

typedef __attribute__((ext_vector_type(8))) short bf16x8;
typedef __attribute__((ext_vector_type(4))) float f32x4;

__device__ __forceinline__ unsigned short f2b(float f) {   // f32 -> bf16 (RNE)
  unsigned int u = __float_as_uint(f);
  return (unsigned short)((u + 0x7FFFu + ((u >> 16) & 1u)) >> 16);
}
__device__ __forceinline__ float b2f(unsigned short s) {
  return __uint_as_float(((unsigned int)s) << 16);
}

// ---------------------------------------------------------------------------
// Kernel A: shifted-window MHA + out-proj + residual.  UNCHANGED from round 1
// (known-good; MFMA rewrite next round once conv2 validates frag layouts).
// ---------------------------------------------------------------------------
__global__ __launch_bounds__(256) void wa_attn(
    const float* __restrict__ x, const float* __restrict__ ipw,
    const float* __restrict__ ipb, const float* __restrict__ opw,
    const float* __restrict__ opb, const float* __restrict__ bt,
    float* __restrict__ y)
{
  __shared__ __align__(16) float sT[6144];     // [96][64]
  __shared__ __align__(16) float sQKV[18432];  // [288][64]
  __shared__ __align__(16) float sO[6208];     // [64][97]
  __shared__ __align__(16) float sW[9216];     // [96][96] staged weights

  const int tid = threadIdx.x;
  const int wid = blockIdx.x;
  const int b   = wid / NWIN_B;
  const int rem = wid - b * NWIN_B;
  const int wy  = rem / 48;
  const int wx  = rem - wy * 48;
  const int tok = tid & 63;
  const int wv  = __builtin_amdgcn_readfirstlane(tid >> 6);

  #pragma unroll
  for (int i = 0; i < 24; ++i) {
    int idx = i * 256 + tid;
    int c = idx >> 6, t = idx & 63;
    int hh = (wy << 3) + (t >> 3) + 4; if (hh >= 384) hh -= 384;
    int ww = (wx << 3) + (t & 7) + 4;  if (ww >= 384) ww -= 384;
    sT[idx] = x[(b * 96 + c) * HW + hh * 384 + ww];
  }

  for (int chunk = 0; chunk < 3; ++chunk) {
    __syncthreads();
    #pragma unroll
    for (int i = 0; i < 36; ++i)
      sW[i * 256 + tid] = ipw[chunk * 9216 + i * 256 + tid];
    __syncthreads();
    #pragma unroll 1
    for (int g = 0; g < 6; ++g) {
      int bl  = g * 16 + wv * 4;
      int dim = chunk * 96 + bl;
      float a0 = ipb[dim], a1 = ipb[dim + 1], a2 = ipb[dim + 2], a3 = ipb[dim + 3];
      #pragma unroll
      for (int c4 = 0; c4 < 24; ++c4) {
        float t0 = sT[(c4 * 4 + 0) * 64 + tok];
        float t1 = sT[(c4 * 4 + 1) * 64 + tok];
        float t2 = sT[(c4 * 4 + 2) * 64 + tok];
        float t3 = sT[(c4 * 4 + 3) * 64 + tok];
        float4 w0 = *(const float4*)&sW[(bl + 0) * 96 + c4 * 4];
        float4 w1 = *(const float4*)&sW[(bl + 1) * 96 + c4 * 4];
        float4 w2 = *(const float4*)&sW[(bl + 2) * 96 + c4 * 4];
        float4 w3 = *(const float4*)&sW[(bl + 3) * 96 + c4 * 4];
        a0 += w0.x * t0 + w0.y * t1 + w0.z * t2 + w0.w * t3;
        a1 += w1.x * t0 + w1.y * t1 + w1.z * t2 + w1.w * t3;
        a2 += w2.x * t0 + w2.y * t1 + w2.z * t2 + w2.w * t3;
        a3 += w3.x * t0 + w3.y * t1 + w3.z * t2 + w3.w * t3;
      }
      sQKV[(dim + 0) * 64 + tok] = a0;
      sQKV[(dim + 1) * 64 + tok] = a1;
      sQKV[(dim + 2) * 64 + tok] = a2;
      sQKV[(dim + 3) * 64 + tok] = a3;
    }
  }
  __syncthreads();

  const int it = tid >> 4, jt = tid & 15;
  const int i0 = it << 2, j0 = jt << 2;

  float msk[16];
  #pragma unroll
  for (int a = 0; a < 4; ++a) {
    int ri = (i0 + a) >> 3, ci = (i0 + a) & 7;
    #pragma unroll
    for (int bb = 0; bb < 4; ++bb) {
      int rj = (j0 + bb) >> 3, cj = (j0 + bb) & 7;
      msk[a * 4 + bb] = bt[(ri - rj + 7) * 15 + (ci - cj + 7)];
    }
  }

  #pragma unroll 1
  for (int h = 0; h < 2; ++h) {
    const float* qp = sQKV + (h * 48) * 64;
    const float* kp = sQKV + (96 + h * 48) * 64;
    const float* vp = sQKV + (192 + h * 48) * 64;
    float acc[16];
    #pragma unroll
    for (int i = 0; i < 16; ++i) acc[i] = 0.f;
    #pragma unroll 4
    for (int d = 0; d < 48; ++d) {
      float4 q4 = *(const float4*)(qp + d * 64 + i0);
      float4 k4 = *(const float4*)(kp + d * 64 + j0);
      acc[0]  += q4.x * k4.x; acc[1]  += q4.x * k4.y; acc[2]  += q4.x * k4.z; acc[3]  += q4.x * k4.w;
      acc[4]  += q4.y * k4.x; acc[5]  += q4.y * k4.y; acc[6]  += q4.y * k4.z; acc[7]  += q4.y * k4.w;
      acc[8]  += q4.z * k4.x; acc[9]  += q4.z * k4.y; acc[10] += q4.z * k4.z; acc[11] += q4.z * k4.w;
      acc[12] += q4.w * k4.x; acc[13] += q4.w * k4.y; acc[14] += q4.w * k4.z; acc[15] += q4.w * k4.w;
    }
    #pragma unroll
    for (int i = 0; i < 16; ++i)
      acc[i] = acc[i] * 0.14433756729740643f + msk[i];

    #pragma unroll
    for (int a = 0; a < 4; ++a) {
      float m0 = fmaxf(fmaxf(acc[a*4], acc[a*4+1]), fmaxf(acc[a*4+2], acc[a*4+3]));
      m0 = fmaxf(m0, __shfl_xor(m0, 1));
      m0 = fmaxf(m0, __shfl_xor(m0, 2));
      m0 = fmaxf(m0, __shfl_xor(m0, 4));
      m0 = fmaxf(m0, __shfl_xor(m0, 8));
      float e0 = __expf(acc[a*4+0] - m0);
      float e1 = __expf(acc[a*4+1] - m0);
      float e2 = __expf(acc[a*4+2] - m0);
      float e3 = __expf(acc[a*4+3] - m0);
      float s0 = e0 + e1 + e2 + e3;
      s0 += __shfl_xor(s0, 1);
      s0 += __shfl_xor(s0, 2);
      s0 += __shfl_xor(s0, 4);
      s0 += __shfl_xor(s0, 8);
      float r = 1.0f / s0;
      acc[a*4+0] = e0 * r; acc[a*4+1] = e1 * r; acc[a*4+2] = e2 * r; acc[a*4+3] = e3 * r;
    }

    #pragma unroll 2
    for (int d = 0; d < 48; ++d) {
      float4 v4 = *(const float4*)(vp + d * 64 + j0);
      float o0 = acc[0]  * v4.x + acc[1]  * v4.y + acc[2]  * v4.z + acc[3]  * v4.w;
      float o1 = acc[4]  * v4.x + acc[5]  * v4.y + acc[6]  * v4.z + acc[7]  * v4.w;
      float o2 = acc[8]  * v4.x + acc[9]  * v4.y + acc[10] * v4.z + acc[11] * v4.w;
      float o3 = acc[12] * v4.x + acc[13] * v4.y + acc[14] * v4.z + acc[15] * v4.w;
      o0 += __shfl_xor(o0, 1); o0 += __shfl_xor(o0, 2); o0 += __shfl_xor(o0, 4); o0 += __shfl_xor(o0, 8);
      o1 += __shfl_xor(o1, 1); o1 += __shfl_xor(o1, 2); o1 += __shfl_xor(o1, 4); o1 += __shfl_xor(o1, 8);
      o2 += __shfl_xor(o2, 1); o2 += __shfl_xor(o2, 2); o2 += __shfl_xor(o2, 4); o2 += __shfl_xor(o2, 8);
      o3 += __shfl_xor(o3, 1); o3 += __shfl_xor(o3, 2); o3 += __shfl_xor(o3, 4); o3 += __shfl_xor(o3, 8);
      if (jt == 0) {
        int cc = h * 48 + d;
        sO[(i0 + 0) * 97 + cc] = o0;
        sO[(i0 + 1) * 97 + cc] = o1;
        sO[(i0 + 2) * 97 + cc] = o2;
        sO[(i0 + 3) * 97 + cc] = o3;
      }
    }
  }
  __syncthreads();

  #pragma unroll
  for (int i = 0; i < 36; ++i)
    sW[i * 256 + tid] = opw[i * 256 + tid];
  __syncthreads();

  int hh = (wy << 3) + (tok >> 3) + 4; if (hh >= 384) hh -= 384;
  int ww = (wx << 3) + (tok & 7) + 4;  if (ww >= 384) ww -= 384;
  const int pix = hh * 384 + ww;

  #pragma unroll 1
  for (int g = 0; g < 6; ++g) {
    int bl = g * 16 + wv * 4;
    float a0 = opb[bl], a1 = opb[bl + 1], a2 = opb[bl + 2], a3 = opb[bl + 3];
    #pragma unroll
    for (int c4 = 0; c4 < 24; ++c4) {
      float t0 = sO[tok * 97 + c4 * 4 + 0];
      float t1 = sO[tok * 97 + c4 * 4 + 1];
      float t2 = sO[tok * 97 + c4 * 4 + 2];
      float t3 = sO[tok * 97 + c4 * 4 + 3];
      float4 w0 = *(const float4*)&sW[(bl + 0) * 96 + c4 * 4];
      float4 w1 = *(const float4*)&sW[(bl + 1) * 96 + c4 * 4];
      float4 w2 = *(const float4*)&sW[(bl + 2) * 96 + c4 * 4];
      float4 w3 = *(const float4*)&sW[(bl + 3) * 96 + c4 * 4];
      a0 += w0.x * t0 + w0.y * t1 + w0.z * t2 + w0.w * t3;
      a1 += w1.x * t0 + w1.y * t1 + w1.z * t2 + w1.w * t3;
      a2 += w2.x * t0 + w2.y * t1 + w2.z * t2 + w2.w * t3;
      a3 += w3.x * t0 + w3.y * t1 + w3.z * t2 + w3.w * t3;
    }
    y[(b * 96 + bl + 0) * HW + pix] = sT[(bl + 0) * 64 + tok] + a0;
    y[(b * 96 + bl + 1) * HW + pix] = sT[(bl + 1) * 64 + tok] + a1;
    y[(b * 96 + bl + 2) * HW + pix] = sT[(bl + 2) * 64 + tok] + a2;
    y[(b * 96 + bl + 3) * HW + pix] = sT[(bl + 3) * 64 + tok] + a3;
  }
}

// ---------------------------------------------------------------------------
// Kernel B: 1x1 conv + exact GELU.  Same as round 1 except output is bf16
// (halves conv2 staging traffic and frees ws space for transposed weights).
// ---------------------------------------------------------------------------
__global__ __launch_bounds__(256) void wa_conv1(
    const float* __restrict__ y, const float* __restrict__ w1,
    const float* __restrict__ b1, unsigned short* __restrict__ hdn)
{
  __shared__ __align__(16) float sW[9216];
  __shared__ float sB[96];
  const int tid = threadIdx.x;
  #pragma unroll
  for (int i = 0; i < 36; ++i) sW[i * 256 + tid] = w1[i * 256 + tid];
  if (tid < 96) sB[tid] = b1[tid];
  __syncthreads();

  const int pix = blockIdx.x * 256 + tid;
  const int b  = pix / HW;
  const int hw = pix - b * HW;
  const float* yp = y + (b * 96) * HW + hw;
  unsigned short* hp = hdn + (b * 96) * HW + hw;

  float yv[96];
  #pragma unroll
  for (int c = 0; c < 96; ++c) yv[c] = yp[c * HW];

  #pragma unroll 1
  for (int o = 0; o < 96; ++o) {
    float a = sB[o];
    const float4* wr = (const float4*)(sW + o * 96);
    #pragma unroll
    for (int c4 = 0; c4 < 24; ++c4) {
      float4 w4 = wr[c4];
      a += w4.x * yv[c4*4+0] + w4.y * yv[c4*4+1] + w4.z * yv[c4*4+2] + w4.w * yv[c4*4+3];
    }
    float g = 0.5f * a * (1.0f + erff(a * 0.70710678118654752f));
    hp[o * HW] = f2b(g);
  }
}

// ---------------------------------------------------------------------------
// Kernel P: transpose conv2 weights -> bf16 wT[tap][o][104c] in workspace.
// ---------------------------------------------------------------------------
__global__ __launch_bounds__(256) void prep_w2(
    const float* __restrict__ c2w, unsigned short* __restrict__ wT)
{
  int i = blockIdx.x * 256 + threadIdx.x;
  if (i >= 82944) return;                       // 9*96*96
  int tap = i / 9216, rr = i - tap * 9216;
  int o = rr / 96, c = rr - o * 96;
  wT[tap * 9984 + o * 104 + c] = f2b(c2w[(o * 96 + c) * 9 + tap]);
}

// ---------------------------------------------------------------------------
// Kernel C: 3x3 conv as 9 shifted 1x1 bf16-MFMA GEMMs + LeakyReLU + residual.
// Block: 16x16 output pixels, 256 thr (4 waves).  M=256 pix, N=96 o, K=96 c/tap.
// LDS: sIn [324 pix][104 c] bf16 (67,392 B) | sW [96 o][104 c] bf16 (19,968 B).
// A-frag: row=pixel (lane&15 -> px), k=c.  B-frag: col=o (lane&15), k=c.
// C/D: col(lane&15)=o, row((lane>>4)*4+r)=px   [guide §3, m89-verified].
// ---------------------------------------------------------------------------
__global__ __launch_bounds__(256) void wa_conv2(
    const unsigned short* __restrict__ hdn, const unsigned short* __restrict__ wT,
    const float* __restrict__ b2, float* __restrict__ out)
{
  __shared__ __align__(16) unsigned short sIn[324 * 104];
  __shared__ __align__(16) unsigned short sW[96 * 104];

  const int tid = threadIdx.x;
  const int bid = blockIdx.x;
  const int b  = bid / 576;
  const int r2 = bid - b * 576;
  const int ty = r2 / 24, tx = r2 - ty * 24;
  const int gy0 = ty * 16, gx0 = tx * 16;

  const int wv = tid >> 6;
  const int ln = tid & 63;
  const int lr = ln & 15;        // px within M-tile / o within N-tile
  const int kg = ln >> 4;        // k-group 0..3

  // ---- stage input tile [18x18 halo][96 c] as bf16, transposed to [pix][c] --
  for (int i = tid; i < 31104; i += 256) {      // 324 * 96
    int c = i / 324, pp = i - c * 324;
    int sy = pp / 18, sx = pp - sy * 18;
    int iy = gy0 + sy - 1; iy = iy < 0 ? 0 : (iy > 383 ? 383 : iy);
    int ix = gx0 + sx - 1; ix = ix < 0 ? 0 : (ix > 383 ? 383 : ix);
    sIn[pp * 104 + c] = hdn[(b * 96 + c) * HW + iy * 384 + ix];
  }

  float b2v[6];
  #pragma unroll
  for (int n = 0; n < 6; ++n) b2v[n] = b2[n * 16 + lr];

  f32x4 acc[4][6];
  #pragma unroll
  for (int m = 0; m < 4; ++m)
    #pragma unroll
    for (int n = 0; n < 6; ++n)
      acc[m][n] = (f32x4){0.f, 0.f, 0.f, 0.f};

  #pragma unroll 1
  for (int tap = 0; tap < 9; ++tap) {
    __syncthreads();                            // sIn ready (tap 0) / prev reads done
    {                                           // stage this tap's weights
      const unsigned int* wsrc = (const unsigned int*)(wT + tap * 9984);
      unsigned int* wdst = (unsigned int*)sW;
      for (int i = tid; i < 4992; i += 256) wdst[i] = wsrc[i];
    }
    __syncthreads();

    const int dy = tap / 3, dx = tap - dy * 3;
    #pragma unroll
    for (int kk = 0; kk < 3; ++kk) {
      const int kb = kk * 32 + kg * 8;          // element col (c)
      bf16x8 a0 = *(const bf16x8*)(sIn + ((4 * wv + 0 + dy) * 18 + dx + lr) * 104 + kb);
      bf16x8 a1 = *(const bf16x8*)(sIn + ((4 * wv + 1 + dy) * 18 + dx + lr) * 104 + kb);
      bf16x8 a2 = *(const bf16x8*)(sIn + ((4 * wv + 2 + dy) * 18 + dx + lr) * 104 + kb);
      bf16x8 a3 = *(const bf16x8*)(sIn + ((4 * wv + 3 + dy) * 18 + dx + lr) * 104 + kb);
      #pragma unroll
      for (int n = 0; n < 6; ++n) {
        bf16x8 bfr = *(const bf16x8*)(sW + (n * 16 + lr) * 104 + kb);
        acc[0][n] = __builtin_amdgcn_mfma_f32_16x16x32_bf16(a0, bfr, acc[0][n], 0, 0, 0);
        acc[1][n] = __builtin_amdgcn_mfma_f32_16x16x32_bf16(a1, bfr, acc[1][n], 0, 0, 0);
        acc[2][n] = __builtin_amdgcn_mfma_f32_16x16x32_bf16(a2, bfr, acc[2][n], 0, 0, 0);
        acc[3][n] = __builtin_amdgcn_mfma_f32_16x16x32_bf16(a3, bfr, acc[3][n], 0, 0, 0);
      }
    }
  }

  // ---- epilogue: bias + LeakyReLU -> sOut[o][256 pix] (aliases sIn) --------
  __syncthreads();
  unsigned short* sOut = sIn;                   // 96*264 = 25,344 elems <= 33,696
  #pragma unroll
  for (int m = 0; m < 4; ++m) {
    const int py = 4 * wv + m;
    #pragma unroll
    for (int n = 0; n < 6; ++n) {
      const int o = n * 16 + lr;
      #pragma unroll
      for (int r = 0; r < 4; ++r) {
        float v = acc[m][n][r] + b2v[n];
        v = v >= 0.f ? v : 0.1f * v;
        sOut[o * 264 + py * 16 + kg * 4 + r] = f2b(v);
      }
    }
  }
  __syncthreads();

  // ---- coalesced residual RMW: out += sOut ---------------------------------
  for (int j = tid; j < 12288; j += 256) {      // 96 * 128 pixel-pairs
    int o = j >> 7, q = j & 127;
    unsigned int pk = *(const unsigned int*)(sOut + o * 264 + q * 2);
    int pp = q * 2;
    int py = pp >> 4, px = pp & 15;
    float* yp = &out[(b * 96 + o) * HW + (gy0 + py) * 384 + gx0 + px];
    float2 old = *(float2*)yp;
    old.x += b2f((unsigned short)(pk & 0xffffu));
    old.y += b2f((unsigned short)(pk >> 16));
    *(float2*)yp = old;
  }
}

// ---------------------------------------------------------------------------
extern "C" void kernel_launch(void* const* d_in, const int* in_sizes, int n_in,
                              void* d_out, int out_size, void* d_ws, size_t ws_size,
                              hipStream_t stream) {
  const float* x   = (const float*)d_in[0];
  const float* ipw = (const float*)d_in[1];
  const float* ipb = (const float*)d_in[2];
  const float* opw = (const float*)d_in[3];
  const float* opb = (const float*)d_in[4];
  const float* c1w = (const float*)d_in[5];
  const float* c1b = (const float*)d_in[6];
  const float* c2w = (const float*)d_in[7];
  const float* c2b = (const float*)d_in[8];
  const float* bt  = (const float*)d_in[9];
  float* y = (float*)d_out;
  // ws layout: [0, 113,246,208) hdn bf16 ; [113,246,208, +179,712) wT bf16
  unsigned short* hdn = (unsigned short*)d_ws;
  unsigned short* wT  = (unsigned short*)d_ws + 56623104;

  prep_w2 <<<dim3(324),        dim3(256), 0, stream>>>(c2w, wT);
  wa_attn <<<dim3(4 * NWIN_B), dim3(256), 0, stream>>>(x, ipw, ipb, opw, opb, bt, y);
  wa_conv1<<<dim3(2304),       dim3(256), 0, stream>>>(y, c1w, c1b, hdn);
  wa_conv2<<<dim3(2304),       dim3(256), 0, stream>>>(hdn, wT, c2b, y);
}